// Round 14
// baseline (94.037 us; speedup 1.0000x reference)
//
#include <hip/hip_runtime.h>

#define NG 512
#define PLANE 512

typedef float v2f __attribute__((ext_vector_type(2)));

// ws layout (float index):
//   [4352 .. 4864)          : per-ROW max slots rowmax[r] = max_n,x log2(prob)
//   [8192 .. 8192+512*512*8): table [row][n] = {A, beta, gamma, wr, wg, wb, 0, 0}
#define SLOT_OFF 4352
#define TBL_OFF  8192

// One block per ROW (512 blocks x 512 threads, thread = gaussian).
// Each thread recomputes its gaussian's params (HW trig/rcp, redundant across
// blocks -- trivial), derives the row-expanded quadratic
//   q(u) = u*(A*u + beta) + gamma,  u = x - 1/2,
// writes one coalesced 32B table entry, and contributes the exact discrete
// row max of t = log2(prob) (concave parabola in x -> vertex +/- lattice
// candidates, dx-form for accuracy) to a block max-reduce -> rowmax[row].
__global__ __launch_bounds__(512) void prep_kernel(
    const float* __restrict__ mean, const float* __restrict__ alpha,
    const float* __restrict__ scale, const float* __restrict__ theta,
    const float* __restrict__ rgb, float* __restrict__ ws) {
    const int row = blockIdx.x;         // 0..511
    const int n   = threadIdx.x;        // 0..511 (gaussian)

    const float TWO_PI = 6.283185307179586f;
    float th = theta[n];
    float c = __builtin_amdgcn_cosf(th);   // cos(2*pi*th): v_cos takes revolutions
    float s = __builtin_amdgcn_sinf(th);
    float sx = scale[2 * n], sy = scale[2 * n + 1];

    // cov = rot @ smat @ smat^T @ rot^T (reference f32 order)
    float m200 = (c * sx) * sx;
    float m201 = (-(s * sy)) * sy;
    float m210 = (s * sx) * sx;
    float m211 = (c * sy) * sy;
    float a   = m200 * c + m201 * (-s);
    float b01 = m200 * s + m201 * c;
    float b10 = m210 * c + m211 * (-s);
    float d   = m210 * s + m211 * c;

    float det = a * d - b01 * b10;
    float rdet = __builtin_amdgcn_rcpf(det);
    float inv00 = d * rdet;
    float inv01 = -b01 * rdet;
    float inv10 = -b10 * rdet;
    float inv11 = a * rdet;

    float norm = __builtin_amdgcn_rcpf(TWO_PI * __builtin_amdgcn_sqrtf(det));
    const float K = -0.5f * 1.4426950408889634f;  // -0.5 * log2(e)

    float A_ = K * inv00;
    float B_ = K * (inv01 + inv10);
    float C_ = K * inv11;
    float mx = mean[2 * n], my = mean[2 * n + 1];
    // Lg = log2(norm) = -log2(2*pi) - 0.5*log2(det)
    float Lg = fmaf(-0.5f, __builtin_amdgcn_logf(det), -2.651496129472319f);
    float w  = alpha[n] * norm;

    const float STEP = 1.0f / 511.0f;
    float y  = (float)row * STEP;
    float dy = y - my;
    float bdy  = B_ * dy;
    float cdy2 = C_ * (dy * dy);

    // expanded row quadratic around u = x - 1/2
    float mxp   = mx - 0.5f;
    float beta  = fmaf(-2.0f * A_, mxp, bdy);
    float gamma = fmaf(fmaf(A_, mxp, -bdy), mxp, cdy2);

    float4* te = (float4*)(ws + TBL_OFF + ((size_t)(row << 9) + n) * 8);
    te[0] = make_float4(A_, beta, gamma, w * rgb[3 * n]);
    te[1] = make_float4(w * rgb[3 * n + 1], w * rgb[3 * n + 2], 0.f, 0.f);

    // exact discrete row max (dx-form, accurate)
    float inv2A = __builtin_amdgcn_rcpf(2.0f * A_);
    float xstar = mx - bdy * inv2A;
    float xs = fminf(fmaxf(xstar, 0.0f), 1.0f);   // NaN-safe clamp
    int i1 = min((int)(xs * 511.0f), 510);
    float t = -1e30f;
#pragma unroll
    for (int kk = -1; kk <= 2; ++kk) {
        int i = max(0, min(i1 + kk, 511));
        float x = (float)i * STEP;
        float dx = x - mx;
        float q = fmaf(fmaf(A_, dx, bdy), dx, cdy2);
        t = fmaxf(t, q);
    }
    t += Lg;

    // block max-reduce (8 waves)
#pragma unroll
    for (int off = 32; off > 0; off >>= 1)
        t = fmaxf(t, __shfl_xor(t, off));
    __shared__ float sm[8];
    if ((n & 63) == 0) sm[n >> 6] = t;
    __syncthreads();
    if (n == 0) {
        float mm = sm[0];
#pragma unroll
        for (int wv2 = 1; wv2 < 8; ++wv2) mm = fmaxf(mm, sm[wv2]);
        ws[SLOT_OFF + row] = mm;
    }
}

// 512 blocks x 512 threads: one block per image row, 8 px/lane. Wave wv
// handles gaussians [wv*64,(wv+1)*64) (readfirstlane -> s_load path on the
// row table, 2-deep rotate prefetch). Per gaussian: q = u*(A*u+beta)+gamma
// (8 pk-fma) + 8 exp2 + 12 acc pk-fma -- no dx/dy work in the loop.
// All waves redundantly reduce the 512 rowmax slots; 8-chunk partials combine
// in LDS with the epilogue spread over 384 threads (one float4, coalesced).
__global__ __launch_bounds__(512, 2) void splat_kernel(
    const float* __restrict__ pixels, const float* __restrict__ ws,
    float* __restrict__ out) {
    const int tid  = threadIdx.x;
    const int wv   = __builtin_amdgcn_readfirstlane(tid >> 6);  // 0..7
    const int lane = tid & 63;
    const int row  = blockIdx.x;                 // 0..511
    const int px0  = (row << 9) + (lane << 3);   // first of 8 consecutive px

    // 4 dwordx4: {x0,y,x1,y}{x2,y,x3,y}{x4,y,x5,y}{x6,y,x7,y}
    const float4* pp = reinterpret_cast<const float4*>(pixels + 2 * px0);
    float4 pA = pp[0], pB = pp[1], pC = pp[2], pD = pp[3];
    const v2f half2 = {0.5f, 0.5f};
    const v2f u01 = (v2f){pA.x, pA.z} - half2;
    const v2f u23 = (v2f){pB.x, pB.z} - half2;
    const v2f u45 = (v2f){pC.x, pC.z} - half2;
    const v2f u67 = (v2f){pD.x, pD.z} - half2;

    const float4* tbl = reinterpret_cast<const float4*>(ws + TBL_OFF)
                        + ((size_t)row << 10) + (wv << 7);

    v2f ar01 = {0.f, 0.f}, ag01 = {0.f, 0.f}, ab01 = {0.f, 0.f};
    v2f ar23 = {0.f, 0.f}, ag23 = {0.f, 0.f}, ab23 = {0.f, 0.f};
    v2f ar45 = {0.f, 0.f}, ag45 = {0.f, 0.f}, ab45 = {0.f, 0.f};
    v2f ar67 = {0.f, 0.f}, ag67 = {0.f, 0.f}, ab67 = {0.f, 0.f};

    float4 ta = tbl[0];
    float4 tb = tbl[1];
#pragma unroll 4
    for (int n = 0; n < 64; ++n) {
        float4 na = tbl[2 * n + 2];   // prefetch next entry (n=63 reads next
        float4 nb = tbl[2 * n + 3];   // chunk/table row -- valid memory)

        float A_ = ta.x, beta = ta.y, gamma = ta.z, wr = ta.w;
        float wg = tb.x, wb = tb.y;
        v2f Av = {A_, A_}, bev = {beta, beta}, gav = {gamma, gamma};

        v2f t01 = __builtin_elementwise_fma(u01, Av, bev);
        v2f t23 = __builtin_elementwise_fma(u23, Av, bev);
        v2f t45 = __builtin_elementwise_fma(u45, Av, bev);
        v2f t67 = __builtin_elementwise_fma(u67, Av, bev);
        v2f q01 = __builtin_elementwise_fma(t01, u01, gav);
        v2f q23 = __builtin_elementwise_fma(t23, u23, gav);
        v2f q45 = __builtin_elementwise_fma(t45, u45, gav);
        v2f q67 = __builtin_elementwise_fma(t67, u67, gav);

        v2f e01 = {__builtin_amdgcn_exp2f(q01.x), __builtin_amdgcn_exp2f(q01.y)};
        v2f e23 = {__builtin_amdgcn_exp2f(q23.x), __builtin_amdgcn_exp2f(q23.y)};
        v2f e45 = {__builtin_amdgcn_exp2f(q45.x), __builtin_amdgcn_exp2f(q45.y)};
        v2f e67 = {__builtin_amdgcn_exp2f(q67.x), __builtin_amdgcn_exp2f(q67.y)};

        v2f wrv = {wr, wr}, wgv = {wg, wg}, wbv = {wb, wb};
        ar01 = __builtin_elementwise_fma(e01, wrv, ar01);
        ag01 = __builtin_elementwise_fma(e01, wgv, ag01);
        ab01 = __builtin_elementwise_fma(e01, wbv, ab01);
        ar23 = __builtin_elementwise_fma(e23, wrv, ar23);
        ag23 = __builtin_elementwise_fma(e23, wgv, ag23);
        ab23 = __builtin_elementwise_fma(e23, wbv, ab23);
        ar45 = __builtin_elementwise_fma(e45, wrv, ar45);
        ag45 = __builtin_elementwise_fma(e45, wgv, ag45);
        ab45 = __builtin_elementwise_fma(e45, wbv, ab45);
        ar67 = __builtin_elementwise_fma(e67, wrv, ar67);
        ag67 = __builtin_elementwise_fma(e67, wgv, ag67);
        ab67 = __builtin_elementwise_fma(e67, wbv, ab67);

        ta = na; tb = nb;
    }

    // rowmax reduce: redundant in EVERY wave (keeps epilogue independent)
    float invmax;
    {
        const float4* sl = reinterpret_cast<const float4*>(ws + SLOT_OFF) + 2 * lane;
        float4 s0 = sl[0], s1 = sl[1];
        float m = fmaxf(fmaxf(fmaxf(s0.x, s0.y), fmaxf(s0.z, s0.w)),
                        fmaxf(fmaxf(s1.x, s1.y), fmaxf(s1.z, s1.w)));
#pragma unroll
        for (int off = 32; off > 0; off >>= 1)
            m = fmaxf(m, __shfl_xor(m, off));
        invmax = __builtin_amdgcn_exp2f(-m);   // 1 / max(prob)
    }

    // pack partials px-major (24 floats = 6 float4 per lane-chunk)
    __shared__ float4 red[8][64][6];
    red[wv][lane][0] = make_float4(ar01.x, ag01.x, ab01.x, ar01.y);
    red[wv][lane][1] = make_float4(ag01.y, ab01.y, ar23.x, ag23.x);
    red[wv][lane][2] = make_float4(ab23.x, ar23.y, ag23.y, ab23.y);
    red[wv][lane][3] = make_float4(ar45.x, ag45.x, ab45.x, ar45.y);
    red[wv][lane][4] = make_float4(ag45.y, ab45.y, ar67.x, ag67.x);
    red[wv][lane][5] = make_float4(ab67.x, ar67.y, ag67.y, ab67.y);
    __syncthreads();

    // epilogue over 384 threads: sum one float4 across 8 chunks, sigmoid,
    // coalesced store (row region = 384 consecutive float4)
    if (tid < 384) {
        const int l    = tid / 6;
        const int slot = tid - 6 * l;
        float4 v = red[0][l][slot];
#pragma unroll
        for (int cch = 1; cch < 8; ++cch) {
            float4 u = red[cch][l][slot];
            v.x += u.x; v.y += u.y; v.z += u.z; v.w += u.w;
        }
        const float KE = 1.4426950408889634f;  // log2(e)
#define SIG(x) __builtin_amdgcn_rcpf(1.0f + __builtin_amdgcn_exp2f(-KE * ((x) * invmax)))
        v.x = SIG(v.x); v.y = SIG(v.y); v.z = SIG(v.z); v.w = SIG(v.w);
#undef SIG
        reinterpret_cast<float4*>(out)[row * 384 + tid] = v;
    }
}

extern "C" void kernel_launch(void* const* d_in, const int* in_sizes, int n_in,
                              void* d_out, int out_size, void* d_ws, size_t ws_size,
                              hipStream_t stream) {
    const float* mean   = (const float*)d_in[0];
    const float* alpha  = (const float*)d_in[1];
    const float* scale  = (const float*)d_in[2];
    const float* theta  = (const float*)d_in[3];
    const float* rgb    = (const float*)d_in[4];
    const float* pixels = (const float*)d_in[5];
    float* out = (float*)d_out;
    float* ws  = (float*)d_ws;

    // one block per row: coalesced table write + row max
    prep_kernel<<<512, 512, 0, stream>>>(mean, alpha, scale, theta, rgb, ws);

    // one block per image row: 512 blocks x 512 threads, 8 px/lane
    splat_kernel<<<512, 512, 0, stream>>>(pixels, ws, out);
}

// Round 15
// 91.039 us; speedup vs baseline: 1.0329x; 1.0329x over previous
//
#include <hip/hip_runtime.h>

#define NG 512
#define PLANE 512

typedef float v2f __attribute__((ext_vector_type(2)));

// ws layout (float index):
//   [16 .. 16+8*513)   : packed params, 8 floats per gaussian:
//                        {A, B, C, mx, my, wr, wg, wb} (entry 512 = pad)
//   [4352 .. 4864)     : per-gaussian max slots t[n] = max log2(prob_n)
#define PRM_OFF  16
#define SLOT_OFF 4352

// One block (256 thr) per gaussian. All threads compute the params redundantly
// (HW trig/rcp); thread 0 publishes them. Each thread scans 2 rows using
// ANALYTIC coordinates (grid = linspace(0,1,512), x_i = i/511): exact discrete
// max of t = log2(prob) per row (concave parabola in x -> vertex +/- lattice
// candidates), then wave+LDS max-reduce -> slot[n]. No global loads in scan.
__global__ __launch_bounds__(256) void prep_kernel(
    const float* __restrict__ mean, const float* __restrict__ alpha,
    const float* __restrict__ scale, const float* __restrict__ theta,
    const float* __restrict__ rgb, float* __restrict__ ws) {
    const int n   = blockIdx.x;         // 0..511
    const int tid = threadIdx.x;        // 0..255

    const float TWO_PI = 6.283185307179586f;
    float th = theta[n];
    float c = __builtin_amdgcn_cosf(th);   // cos(2*pi*th): v_cos takes revolutions
    float s = __builtin_amdgcn_sinf(th);
    float sx = scale[2 * n], sy = scale[2 * n + 1];

    // cov = rot @ smat @ smat^T @ rot^T (reference f32 order)
    float m200 = (c * sx) * sx;
    float m201 = (-(s * sy)) * sy;
    float m210 = (s * sx) * sx;
    float m211 = (c * sy) * sy;
    float a   = m200 * c + m201 * (-s);
    float b01 = m200 * s + m201 * c;
    float b10 = m210 * c + m211 * (-s);
    float d   = m210 * s + m211 * c;

    float det = a * d - b01 * b10;
    float rdet = __builtin_amdgcn_rcpf(det);
    float inv00 = d * rdet;
    float inv01 = -b01 * rdet;
    float inv10 = -b10 * rdet;
    float inv11 = a * rdet;

    float norm = __builtin_amdgcn_rcpf(TWO_PI * __builtin_amdgcn_sqrtf(det));
    const float K = -0.5f * 1.4426950408889634f;  // -0.5 * log2(e)

    float A_ = K * inv00;
    float B_ = K * (inv01 + inv10);
    float C_ = K * inv11;
    float mx = mean[2 * n], my = mean[2 * n + 1];
    // Lg = log2(norm) = -log2(2*pi) - 0.5*log2(det)
    float Lg = fmaf(-0.5f, __builtin_amdgcn_logf(det), -2.651496129472319f);

    if (tid == 0) {
        float w = alpha[n] * norm;
        float4* p = (float4*)(ws + PRM_OFF + 8 * n);
        p[0] = make_float4(A_, B_, C_, mx);
        p[1] = make_float4(my, w * rgb[3 * n], w * rgb[3 * n + 1], w * rgb[3 * n + 2]);
    }

    const float STEP = 1.0f / 511.0f;
    float inv2A = __builtin_amdgcn_rcpf(2.0f * A_);
    float t = -1e30f;
#pragma unroll
    for (int k = 0; k < 2; ++k) {
        int r = tid + (k << 8);
        float y  = (float)r * STEP;
        float dy = y - my;
        float bdy  = B_ * dy;
        float cdy2 = C_ * (dy * dy);
        float xstar = mx - bdy * inv2A;
        float xs = fminf(fmaxf(xstar, 0.0f), 1.0f);   // NaN-safe clamp
        int i1 = min((int)(xs * 511.0f), 510);
#pragma unroll
        for (int kk = -1; kk <= 2; ++kk) {
            int i = max(0, min(i1 + kk, 511));
            float x = (float)i * STEP;
            float dx = x - mx;
            float q = fmaf(fmaf(A_, dx, bdy), dx, cdy2);
            t = fmaxf(t, q);
        }
    }
    t += Lg;

#pragma unroll
    for (int off = 32; off > 0; off >>= 1)
        t = fmaxf(t, __shfl_xor(t, off));
    __shared__ float sm[4];
    if ((tid & 63) == 0) sm[tid >> 6] = t;
    __syncthreads();
    if (tid == 0) {
        float mm = fmaxf(fmaxf(sm[0], sm[1]), fmaxf(sm[2], sm[3]));
        ws[SLOT_OFF + n] = mm;
    }
}

// 1024 blocks x 512 threads (4 blocks/CU target). Block covers 256 px of one
// row (quad = 4 px/lane). STAGE: thread t loads gaussian t's params, hoists
// the block-row dy-terms (bdy, cdy2 -- same expressions as before, bit-
// identical), writes {A,mx,bdy,cdy2|wr,wg,wb,0} to LDS. LOOP: wave wv reads
// its 64-gaussian chunk from LDS (uniform addr -> broadcast, in-order ->
// pipelined lgkmcnt), 12 pk-VALU + 4 exp2 per gaussian. Partials combine via
// the same LDS buffer (union, post-loop barrier); 192-thread epilogue.
__global__ __launch_bounds__(512, 4) void splat_kernel(
    const float* __restrict__ pixels, const float* __restrict__ ws,
    float* __restrict__ out) {
    const int tid  = threadIdx.x;
    const int wv   = __builtin_amdgcn_readfirstlane(tid >> 6);  // 0..7
    const int lane = tid & 63;
    const int quad = blockIdx.x * 64 + lane;     // 0..65535
    const int pbase = quad << 2;                 // first pixel of the quad
    const int row  = blockIdx.x >> 1;            // block-uniform row

    __shared__ float4 shbuf[1536];               // 24576 B (params, then red)

    // ---- stage params + hoist dy-terms (thread t = gaussian t) ----
    {
        const float4* p = reinterpret_cast<const float4*>(ws + PRM_OFF) + 2 * tid;
        float4 p0 = p[0];                        // {A, B, C, mx}
        float4 p1 = p[1];                        // {my, wr, wg, wb}
        float yb = pixels[(row << 10) + 1];      // block row's y (broadcast)
        float dy   = yb - p1.x;
        float bdy  = p0.y * dy;
        float cdy2 = p0.z * (dy * dy);
        shbuf[2 * tid]     = make_float4(p0.x, p0.w, bdy, cdy2);  // {A,mx,bdy,cdy2}
        shbuf[2 * tid + 1] = make_float4(p1.y, p1.z, p1.w, 0.f);  // {wr,wg,wb,0}
    }
    __syncthreads();

    // two dwordx4: {x0,y,x1,y}, {x2,y,x3,y}
    float4 p01 = *reinterpret_cast<const float4*>(pixels + 2 * pbase);
    float4 p23 = *reinterpret_cast<const float4*>(pixels + 2 * pbase + 4);
    const v2f x01 = {p01.x, p01.z};
    const v2f x23 = {p23.x, p23.z};

    v2f ar01 = {0.f, 0.f}, ag01 = {0.f, 0.f}, ab01 = {0.f, 0.f};
    v2f ar23 = {0.f, 0.f}, ag23 = {0.f, 0.f}, ab23 = {0.f, 0.f};

    const float4* chunk = shbuf + (wv << 7);     // 64 entries * 2 float4
#pragma unroll 8
    for (int n = 0; n < 64; ++n) {
        float4 ta = chunk[2 * n];                // {A, mx, bdy, cdy2}
        float4 tb = chunk[2 * n + 1];            // {wr, wg, wb, 0}

        float A_ = ta.x, mx = ta.y, bdy = ta.z, cdy2 = ta.w;
        v2f Av = {A_, A_}, mxv = {mx, mx}, bdyv = {bdy, bdy}, cdv = {cdy2, cdy2};

        v2f dx01 = x01 - mxv;
        v2f dx23 = x23 - mxv;
        v2f t01 = __builtin_elementwise_fma(Av, dx01, bdyv);
        v2f t23 = __builtin_elementwise_fma(Av, dx23, bdyv);
        v2f q01 = __builtin_elementwise_fma(t01, dx01, cdv);
        v2f q23 = __builtin_elementwise_fma(t23, dx23, cdv);

        v2f e01 = {__builtin_amdgcn_exp2f(q01.x), __builtin_amdgcn_exp2f(q01.y)};
        v2f e23 = {__builtin_amdgcn_exp2f(q23.x), __builtin_amdgcn_exp2f(q23.y)};

        v2f wrv = {tb.x, tb.x}, wgv = {tb.y, tb.y}, wbv = {tb.z, tb.z};
        ar01 = __builtin_elementwise_fma(e01, wrv, ar01);
        ag01 = __builtin_elementwise_fma(e01, wgv, ag01);
        ab01 = __builtin_elementwise_fma(e01, wbv, ab01);
        ar23 = __builtin_elementwise_fma(e23, wrv, ar23);
        ag23 = __builtin_elementwise_fma(e23, wgv, ag23);
        ab23 = __builtin_elementwise_fma(e23, wbv, ab23);
    }

    // slot-max reduce: redundant in every wave (no cross-wave dependency)
    float invmax;
    {
        const float4* sl = reinterpret_cast<const float4*>(ws + SLOT_OFF) + 2 * lane;
        float4 s0 = sl[0], s1 = sl[1];
        float m = fmaxf(fmaxf(fmaxf(s0.x, s0.y), fmaxf(s0.z, s0.w)),
                        fmaxf(fmaxf(s1.x, s1.y), fmaxf(s1.z, s1.w)));
#pragma unroll
        for (int off = 32; off > 0; off >>= 1)
            m = fmaxf(m, __shfl_xor(m, off));
        invmax = __builtin_amdgcn_exp2f(-m);   // 1 / max(prob)
    }

    // all waves done reading params -> safe to overwrite shbuf as red buffer
    __syncthreads();

    // pack partials px-major: [r0 g0 b0 r1 | g1 b1 r2 g2 | b2 r3 g3 b3]
    {
        const int base = ((wv << 6) + lane) * 3;
        shbuf[base + 0] = make_float4(ar01.x, ag01.x, ab01.x, ar01.y);
        shbuf[base + 1] = make_float4(ag01.y, ab01.y, ar23.x, ag23.x);
        shbuf[base + 2] = make_float4(ab23.x, ar23.y, ag23.y, ab23.y);
    }
    __syncthreads();

    // epilogue over 192 threads: sum one float4 across 8 chunks, sigmoid,
    // coalesced store (block region = 192 consecutive float4)
    if (tid < 192) {
        const int l    = tid / 3;
        const int slot = tid - 3 * l;
        float4 v = shbuf[l * 3 + slot];
#pragma unroll
        for (int cch = 1; cch < 8; ++cch) {
            float4 u = shbuf[((cch << 6) + l) * 3 + slot];
            v.x += u.x; v.y += u.y; v.z += u.z; v.w += u.w;
        }
        const float KE = 1.4426950408889634f;  // log2(e)
#define SIG(x) __builtin_amdgcn_rcpf(1.0f + __builtin_amdgcn_exp2f(-KE * ((x) * invmax)))
        v.x = SIG(v.x); v.y = SIG(v.y); v.z = SIG(v.z); v.w = SIG(v.w);
#undef SIG
        reinterpret_cast<float4*>(out)[blockIdx.x * 192 + tid] = v;
    }
}

extern "C" void kernel_launch(void* const* d_in, const int* in_sizes, int n_in,
                              void* d_out, int out_size, void* d_ws, size_t ws_size,
                              hipStream_t stream) {
    const float* mean   = (const float*)d_in[0];
    const float* alpha  = (const float*)d_in[1];
    const float* scale  = (const float*)d_in[2];
    const float* theta  = (const float*)d_in[3];
    const float* rgb    = (const float*)d_in[4];
    const float* pixels = (const float*)d_in[5];
    float* out = (float*)d_out;
    float* ws  = (float*)d_ws;

    // one block per gaussian, load-free analytic max scan
    prep_kernel<<<512, 256, 0, stream>>>(mean, alpha, scale, theta, rgb, ws);

    // 65536 pixel-quads / 64 per block = 1024 blocks x 512 threads
    splat_kernel<<<1024, 512, 0, stream>>>(pixels, ws, out);
}